// Round 1
// baseline (454.622 us; speedup 1.0000x reference)
//
#include <hip/hip_runtime.h>

#define DEMB 128

// ---------- precompute: Wc[l][j][k] = sum_m gcn[l][j][m]*lin[l][m][k], stored transposed wt[l][k][j]
__global__ void k_wcomb(const float* __restrict__ lin, const float* __restrict__ gcn,
                        float* __restrict__ wt) {
  int l = blockIdx.x >> 7;
  int k = blockIdx.x & 127;
  int j = threadIdx.x;  // 128 threads
  const float* gl = gcn + ((size_t)l * DEMB + j) * DEMB;
  const float* ll = lin + (size_t)l * DEMB * DEMB + k;
  float acc = 0.f;
#pragma unroll 8
  for (int m = 0; m < DEMB; ++m) acc += gl[m] * ll[(size_t)m * DEMB];
  wt[((size_t)l * DEMB + k) * DEMB + j] = acc;
}

__global__ void k_init(int* __restrict__ deg, int* __restrict__ cur, int n) {
  int i = blockIdx.x * 256 + threadIdx.x;
  if (i < n) { deg[i] = 1; cur[i] = 0; }  // 1 = self loop
}

__global__ void k_deg(const int* __restrict__ ei, int* __restrict__ deg, int etot) {
  int i = blockIdx.x * 256 + threadIdx.x;
  if (i < etot) atomicAdd(&deg[ei[etot + i]], 1);
}

__global__ void k_dinv(const int* __restrict__ deg, float* __restrict__ dinv, int n) {
  int i = blockIdx.x * 256 + threadIdx.x;
  if (i < n) dinv[i] = rsqrtf((float)deg[i]);
}

__global__ void k_scan1(const int* __restrict__ deg, int* __restrict__ off,
                        int* __restrict__ bsum, int n) {
  __shared__ int s[256];
  int t = threadIdx.x, i = blockIdx.x * 256 + t;
  int c = (i < n) ? (deg[i] - 1) : 0;  // edge-only count (self loop handled separately)
  s[t] = c;
  __syncthreads();
  for (int o = 1; o < 256; o <<= 1) {
    int v = (t >= o) ? s[t - o] : 0;
    __syncthreads();
    s[t] += v;
    __syncthreads();
  }
  if (i < n) off[i] = s[t] - c;
  if (t == 255) bsum[blockIdx.x] = s[t];
}

__global__ void k_scan2(const int* __restrict__ bsum, int* __restrict__ boff,
                        int nb, int* __restrict__ off, int n, int etot) {
  __shared__ int s[256];
  int t = threadIdx.x;
  int c = (t < nb) ? bsum[t] : 0;
  s[t] = c;
  __syncthreads();
  for (int o = 1; o < 256; o <<= 1) {
    int v = (t >= o) ? s[t - o] : 0;
    __syncthreads();
    s[t] += v;
    __syncthreads();
  }
  if (t < nb) boff[t] = s[t] - c;
  if (t == 0) off[n] = etot;
}

__global__ void k_scan3(int* __restrict__ off, const int* __restrict__ boff, int n) {
  int i = blockIdx.x * 256 + threadIdx.x;
  if (i < n) off[i] += boff[i >> 8];
}

__global__ void k_fill(const int* __restrict__ ei, const int* __restrict__ off,
                       int* __restrict__ cur, int* __restrict__ csr, int etot) {
  int i = blockIdx.x * 256 + threadIdx.x;
  if (i < etot) {
    int d = ei[etot + i];
    int p = atomicAdd(&cur[d], 1);
    csr[off[d] + p] = ei[i];
  }
}

// ---------- per-layer GEMM: g[i][c] = dinv[i] * sum_k x[i][k] * Wc[c][k]
// 128x128 tile / block, K tiled by 32, x^T staged with XOR swizzle (r ^ (k&28)).
__launch_bounds__(256)
__global__ void k_gemm(const float* __restrict__ x, const float* __restrict__ wt,
                       const float* __restrict__ dinv, float* __restrict__ g, int n) {
  __shared__ float ws[32 * 128];  // ws[kk][c]
  __shared__ float xs[32 * 128];  // xs[kk][r ^ (kk&28)]
  int t = threadIdx.x;
  int row0 = blockIdx.x * 128;
  int trr = t >> 4, tc = t & 15;
  int r0 = trr * 4, c0 = tc * 4;
  float acc[8][8];
#pragma unroll
  for (int i = 0; i < 8; ++i)
#pragma unroll
    for (int j = 0; j < 8; ++j) acc[i][j] = 0.f;

  int rload = t >> 1;          // 0..127
  int kcl = (t & 1) * 16;      // 0 or 16
  int grl = row0 + rload;

  for (int kt = 0; kt < 4; ++kt) {
    __syncthreads();
    // stage W slice (straight copy; wt rows are k)
#pragma unroll
    for (int i = 0; i < 16; ++i) ws[i * 256 + t] = wt[kt * 32 * 128 + i * 256 + t];
    // stage x^T slice with swizzle
    float u[16];
    if (grl < n) {
      const float4* xp = (const float4*)(x + (size_t)grl * DEMB + kt * 32 + kcl);
#pragma unroll
      for (int q = 0; q < 4; ++q) {
        float4 v = xp[q];
        u[q * 4 + 0] = v.x; u[q * 4 + 1] = v.y; u[q * 4 + 2] = v.z; u[q * 4 + 3] = v.w;
      }
    } else {
#pragma unroll
      for (int q = 0; q < 16; ++q) u[q] = 0.f;
    }
#pragma unroll
    for (int j = 0; j < 16; ++j) {
      int kk = kcl + j;
      xs[kk * 128 + (rload ^ (kk & 28))] = u[j];
    }
    __syncthreads();
#pragma unroll 4
    for (int kk = 0; kk < 32; ++kk) {
      int sw = kk & 28;
      float4 xa = *(const float4*)&xs[kk * 128 + (r0 ^ sw)];
      float4 xb = *(const float4*)&xs[kk * 128 + ((64 + r0) ^ sw)];
      float4 wa = *(const float4*)&ws[kk * 128 + c0];
      float4 wb = *(const float4*)&ws[kk * 128 + 64 + c0];
      float xr[8] = {xa.x, xa.y, xa.z, xa.w, xb.x, xb.y, xb.z, xb.w};
      float wc[8] = {wa.x, wa.y, wa.z, wa.w, wb.x, wb.y, wb.z, wb.w};
#pragma unroll
      for (int i = 0; i < 8; ++i)
#pragma unroll
        for (int j = 0; j < 8; ++j) acc[i][j] += xr[i] * wc[j];
    }
  }
#pragma unroll
  for (int i = 0; i < 8; ++i) {
    int rl = (i < 4) ? (r0 + i) : (64 + r0 + i - 4);
    int gr = row0 + rl;
    if (gr < n) {
      float di = dinv[gr];
      float4 o0 = make_float4(acc[i][0] * di, acc[i][1] * di, acc[i][2] * di, acc[i][3] * di);
      float4 o1 = make_float4(acc[i][4] * di, acc[i][5] * di, acc[i][6] * di, acc[i][7] * di);
      float* gp = g + (size_t)gr * DEMB;
      *(float4*)(gp + c0) = o0;
      *(float4*)(gp + 64 + c0) = o1;
    }
  }
}

// ---------- per-layer aggregation: out[i] = dinv[i]*(g[i] + sum_{src in CSR[i]} g[src]) + bias
__launch_bounds__(256)
__global__ void k_agg(const float* __restrict__ g, const int* __restrict__ csr,
                      const int* __restrict__ off, const float* __restrict__ dinv,
                      const float* __restrict__ bias, float* __restrict__ out, int n) {
  int wid = (int)((blockIdx.x * 256 + threadIdx.x) >> 6);
  int lane = threadIdx.x & 63;
  if (wid >= n) return;
  float2 a0 = *(const float2*)(g + (size_t)wid * DEMB + 2 * lane);  // self loop
  float2 a1 = make_float2(0.f, 0.f);
  int e = off[wid], end = off[wid + 1];
  for (; e + 1 < end; e += 2) {
    int s0 = csr[e], s1 = csr[e + 1];
    float2 v0 = *(const float2*)(g + (size_t)s0 * DEMB + 2 * lane);
    float2 v1 = *(const float2*)(g + (size_t)s1 * DEMB + 2 * lane);
    a0.x += v0.x; a0.y += v0.y;
    a1.x += v1.x; a1.y += v1.y;
  }
  if (e < end) {
    int s0 = csr[e];
    float2 v0 = *(const float2*)(g + (size_t)s0 * DEMB + 2 * lane);
    a0.x += v0.x; a0.y += v0.y;
  }
  float di = dinv[wid];
  float2 b = *(const float2*)(bias + 2 * lane);
  float2 r = make_float2(di * (a0.x + a1.x) + b.x, di * (a0.y + a1.y) + b.y);
  *(float2*)(out + (size_t)wid * DEMB + 2 * lane) = r;
}

extern "C" void kernel_launch(void* const* d_in, const int* in_sizes, int n_in,
                              void* d_out, int out_size, void* d_ws, size_t ws_size,
                              hipStream_t stream) {
  const float* x0 = (const float*)d_in[0];
  const int* ei = (const int*)d_in[1];
  const float* lin = (const float*)d_in[2];
  const float* gcn = (const float*)d_in[3];
  const float* gb = (const float*)d_in[4];
  float* out = (float*)d_out;

  int N = in_sizes[0] / DEMB;              // 50000
  int E = in_sizes[1] / 2;                 // 600000
  int L = in_sizes[2] / (DEMB * DEMB);     // 4

  // carve workspace (~29 MB)
  char* w = (char*)d_ws;
  auto carve = [&](size_t bytes) {
    char* p = w;
    w += (bytes + 255) & ~(size_t)255;
    return p;
  };
  float* wt   = (float*)carve((size_t)L * DEMB * DEMB * 4);
  float* dinv = (float*)carve((size_t)N * 4);
  int* deg    = (int*)carve((size_t)N * 4);
  int* off    = (int*)carve((size_t)(N + 1) * 4);
  int* cur    = (int*)carve((size_t)N * 4);
  int* bsum   = (int*)carve(256 * 4);
  int* boff   = (int*)carve(256 * 4);
  int* csr    = (int*)carve((size_t)E * 4);
  float* g    = (float*)carve((size_t)N * DEMB * 4);
  (void)ws_size; (void)n_in; (void)out_size;

  int nbN = (N + 255) / 256;
  int nbE = (E + 255) / 256;

  k_wcomb<<<L * DEMB, DEMB, 0, stream>>>(lin, gcn, wt);
  k_init<<<nbN, 256, 0, stream>>>(deg, cur, N);
  k_deg<<<nbE, 256, 0, stream>>>(ei, deg, E);
  k_dinv<<<nbN, 256, 0, stream>>>(deg, dinv, N);
  k_scan1<<<nbN, 256, 0, stream>>>(deg, off, bsum, N);
  k_scan2<<<1, 256, 0, stream>>>(bsum, boff, nbN, off, N, E);
  k_scan3<<<nbN, 256, 0, stream>>>(off, boff, N);
  k_fill<<<nbE, 256, 0, stream>>>(ei, off, cur, csr, E);

  const float* xin = x0;
  for (int l = 0; l < L; ++l) {
    k_gemm<<<(N + 127) / 128, 256, 0, stream>>>(xin, wt + (size_t)l * DEMB * DEMB, dinv, g, N);
    k_agg<<<(N + 3) / 4, 256, 0, stream>>>(g, csr, off, dinv, gb + (size_t)l * DEMB, out, N);
    xin = out;
  }
}

// Round 2
// 352.250 us; speedup vs baseline: 1.2906x; 1.2906x over previous
//
#include <hip/hip_runtime.h>

#define DEMB 128

// ---------- Ms[l] = gcn_l @ lin_l (row-major), grid L*128, block 128
__global__ void kwc(const float* __restrict__ gcn, const float* __restrict__ lin,
                    float* __restrict__ Ms) {
  __shared__ float sa[128];
  int l = blockIdx.x >> 7, i = blockIdx.x & 127, j = threadIdx.x;
  sa[j] = gcn[((size_t)l * 128 + i) * 128 + j];
  __syncthreads();
  float acc = 0.f;
#pragma unroll 8
  for (int k = 0; k < 128; ++k) acc += sa[k] * lin[((size_t)l * 128 + k) * 128 + j];
  Ms[((size_t)l * 128 + i) * 128 + j] = acc;
}

// ---------- small 128x128 GEMM: C = A@B (row-major); outT: C[j][i] instead
__global__ void ksg(const float* __restrict__ A, const float* __restrict__ B,
                    float* __restrict__ C, int outT) {
  __shared__ float sa[128];
  int i = blockIdx.x, j = threadIdx.x;
  sa[j] = A[i * 128 + j];
  __syncthreads();
  float acc = 0.f;
#pragma unroll 8
  for (int k = 0; k < 128; ++k) acc += sa[k] * B[k * 128 + j];
  if (outT) C[j * 128 + i] = acc; else C[i * 128 + j] = acc;
}

// ---------- bias chain vectors: cb[0]=M3M2M1b0, cb[1]=M3M2b1, cb[2]=M3b2 (1 block,128 thr)
__global__ void kcvec(const float* __restrict__ Ms, const float* __restrict__ gb,
                      float* __restrict__ cb) {
  __shared__ float t0[128], t1[128];
  int j = threadIdx.x;
  const float* M1 = Ms + 16384;
  const float* M2 = Ms + 2 * 16384;
  const float* M3 = Ms + 3 * 16384;
  float a;
  // cA = M3 M2 M1 b0
  t0[j] = gb[j]; __syncthreads();
  a = 0.f; for (int k = 0; k < 128; ++k) a += M1[j * 128 + k] * t0[k];
  t1[j] = a; __syncthreads();
  a = 0.f; for (int k = 0; k < 128; ++k) a += M2[j * 128 + k] * t1[k];
  __syncthreads(); t0[j] = a; __syncthreads();
  a = 0.f; for (int k = 0; k < 128; ++k) a += M3[j * 128 + k] * t0[k];
  cb[j] = a;
  // cB = M3 M2 b1
  __syncthreads(); t0[j] = gb[128 + j]; __syncthreads();
  a = 0.f; for (int k = 0; k < 128; ++k) a += M2[j * 128 + k] * t0[k];
  t1[j] = a; __syncthreads();
  a = 0.f; for (int k = 0; k < 128; ++k) a += M3[j * 128 + k] * t1[k];
  cb[128 + j] = a;
  // cC = M3 b2
  __syncthreads(); t0[j] = gb[256 + j]; __syncthreads();
  a = 0.f; for (int k = 0; k < 128; ++k) a += M3[j * 128 + k] * t0[k];
  cb[256 + j] = a;
}

// ---------- graph prep
__global__ void kinit(int* __restrict__ deg, int* __restrict__ cur, int n) {
  int i = blockIdx.x * 256 + threadIdx.x;
  if (i < n) { deg[i] = 1; cur[i] = 0; }
}

__global__ void kdeg(const int* __restrict__ ei, int* __restrict__ deg, int etot) {
  int i = blockIdx.x * 256 + threadIdx.x;
  if (i < etot) atomicAdd(&deg[ei[etot + i]], 1);
}

__global__ void kdinv(const int* __restrict__ deg, float* __restrict__ dinv,
                      float* __restrict__ dinv2, int n) {
  int i = blockIdx.x * 256 + threadIdx.x;
  if (i < n) {
    float d = rsqrtf((float)deg[i]);
    dinv[i] = d;
    dinv2[i] = d * d;
  }
}

__global__ void kscan1(const int* __restrict__ deg, int* __restrict__ off,
                       int* __restrict__ bsum, int n) {
  __shared__ int s[256];
  int t = threadIdx.x, i = blockIdx.x * 256 + t;
  int c = (i < n) ? (deg[i] - 1) : 0;
  s[t] = c;
  __syncthreads();
  for (int o = 1; o < 256; o <<= 1) {
    int v = (t >= o) ? s[t - o] : 0;
    __syncthreads();
    s[t] += v;
    __syncthreads();
  }
  if (i < n) off[i] = s[t] - c;
  if (t == 255) bsum[blockIdx.x] = s[t];
}

__global__ void kscan2(const int* __restrict__ bsum, int* __restrict__ boff,
                       int nb, int* __restrict__ off, int n, int etot) {
  __shared__ int s[256];
  int t = threadIdx.x;
  int c = (t < nb) ? bsum[t] : 0;
  s[t] = c;
  __syncthreads();
  for (int o = 1; o < 256; o <<= 1) {
    int v = (t >= o) ? s[t - o] : 0;
    __syncthreads();
    s[t] += v;
    __syncthreads();
  }
  if (t < nb) boff[t] = s[t] - c;
  if (t == 0) off[n] = etot;
}

__global__ void kscan3(int* __restrict__ off, const int* __restrict__ boff, int n) {
  int i = blockIdx.x * 256 + threadIdx.x;
  if (i < n) off[i] += boff[i >> 8];
}

__global__ void kfill(const int* __restrict__ ei, const int* __restrict__ off,
                      int* __restrict__ cur, int* __restrict__ csr, int etot) {
  int i = blockIdx.x * 256 + threadIdx.x;
  if (i < etot) {
    int d = ei[etot + i];
    int p = atomicAdd(&cur[d], 1);
    csr[off[d] + p] = ei[i];
  }
}

// ---------- scalar SpMV for bias u-vectors: u = dinv*(sum a_in[src] + a_in[i]); a_out = dinv*u
__global__ void kspmv(const float* __restrict__ a_in, const float* __restrict__ dinv,
                      const int* __restrict__ csr, const int* __restrict__ off,
                      float* __restrict__ u_out, float* __restrict__ a_out, int n) {
  int i = blockIdx.x * 256 + threadIdx.x;
  if (i >= n) return;
  float s = a_in[i];
  int e = off[i], end = off[i + 1];
  for (; e < end; ++e) s += a_in[csr[e]];
  float u = dinv[i] * s;
  u_out[i] = u;
  a_out[i] = dinv[i] * u;
}

// ---------- aggregation, one wave per node, half-wave per edge, 8 rows in flight
// MODE 0: in = raw x     : gather x[src]*dinv[src], self x[i]*dinv[i], epilogue *dinv2[i]
// MODE 1: in pre-scaled  : plain gather-sum,                           epilogue *dinv2[i]
// MODE 2: in pre-scaled  : plain gather-sum,                           epilogue *dinv[i] (final, raw y)
template <int MODE>
__launch_bounds__(256)
__global__ void kagg(const float* __restrict__ vin, const int* __restrict__ csr,
                     const int* __restrict__ off, const float* __restrict__ dinv,
                     const float* __restrict__ dinv2, float* __restrict__ vout, int n) {
  int wid = (int)((blockIdx.x * 256u + threadIdx.x) >> 6);
  if (wid >= n) return;
  int lane = threadIdx.x & 63;
  int h = lane >> 5, l32 = lane & 31;
  float4 acc;
  if (h == 0) {
    float4 sv = *(const float4*)(vin + (size_t)wid * DEMB + 4 * l32);
    float sc = (MODE == 0) ? dinv[wid] : 1.0f;
    acc = make_float4(sv.x * sc, sv.y * sc, sv.z * sc, sv.w * sc);
  } else {
    acc = make_float4(0.f, 0.f, 0.f, 0.f);
  }
  int e = off[wid] + 4 * h;
  int end = off[wid + 1];
  while (e < end) {
    int em = end - 1;
    int i0 = csr[e];
    int i1 = csr[min(e + 1, em)];
    int i2 = csr[min(e + 2, em)];
    int i3 = csr[min(e + 3, em)];
    float w0 = 1.f;
    float w1 = (e + 1 < end) ? 1.f : 0.f;
    float w2 = (e + 2 < end) ? 1.f : 0.f;
    float w3 = (e + 3 < end) ? 1.f : 0.f;
    if (MODE == 0) {
      w0 = dinv[i0]; w1 *= dinv[i1]; w2 *= dinv[i2]; w3 *= dinv[i3];
    }
    float4 r0 = *(const float4*)(vin + (size_t)i0 * DEMB + 4 * l32);
    float4 r1 = *(const float4*)(vin + (size_t)i1 * DEMB + 4 * l32);
    float4 r2 = *(const float4*)(vin + (size_t)i2 * DEMB + 4 * l32);
    float4 r3 = *(const float4*)(vin + (size_t)i3 * DEMB + 4 * l32);
    acc.x += w0 * r0.x + w1 * r1.x + w2 * r2.x + w3 * r3.x;
    acc.y += w0 * r0.y + w1 * r1.y + w2 * r2.y + w3 * r3.y;
    acc.z += w0 * r0.z + w1 * r1.z + w2 * r2.z + w3 * r3.z;
    acc.w += w0 * r0.w + w1 * r1.w + w2 * r2.w + w3 * r3.w;
    e += 8;
  }
  acc.x += __shfl_xor(acc.x, 32);
  acc.y += __shfl_xor(acc.y, 32);
  acc.z += __shfl_xor(acc.z, 32);
  acc.w += __shfl_xor(acc.w, 32);
  if (h == 0) {
    float s = (MODE == 2) ? dinv[wid] : dinv2[wid];
    *(float4*)(vout + (size_t)wid * DEMB + 4 * l32) =
        make_float4(acc.x * s, acc.y * s, acc.z * s, acc.w * s);
  }
}

// ---------- final GEMM (in-place safe): out[i][c] = sum_k y[i][k]*R[c][k]
//            + u3[i]*cA[c] + u2[i]*cB[c] + u1[i]*cC[c] + b3[c]
__launch_bounds__(256)
__global__ void kgemm(const float* __restrict__ x, const float* __restrict__ wt,
                      const float* __restrict__ u1, const float* __restrict__ u2,
                      const float* __restrict__ u3, const float* __restrict__ cb,
                      const float* __restrict__ b3, float* __restrict__ g, int n) {
  __shared__ float ws[32 * 128];  // ws[kk][c] = R[c][kk]
  __shared__ float xs[32 * 128];  // xs[kk][r ^ (kk&28)]
  int t = threadIdx.x;
  int row0 = blockIdx.x * 128;
  int trr = t >> 4, tc = t & 15;
  int r0 = trr * 4, c0 = tc * 4;
  float acc[8][8];
#pragma unroll
  for (int i = 0; i < 8; ++i)
#pragma unroll
    for (int j = 0; j < 8; ++j) acc[i][j] = 0.f;

  int rload = t >> 1;
  int kcl = (t & 1) * 16;
  int grl = row0 + rload;

  for (int kt = 0; kt < 4; ++kt) {
    __syncthreads();
#pragma unroll
    for (int i = 0; i < 16; ++i) ws[i * 256 + t] = wt[kt * 32 * 128 + i * 256 + t];
    float u[16];
    if (grl < n) {
      const float4* xp = (const float4*)(x + (size_t)grl * DEMB + kt * 32 + kcl);
#pragma unroll
      for (int q = 0; q < 4; ++q) {
        float4 v = xp[q];
        u[q * 4 + 0] = v.x; u[q * 4 + 1] = v.y; u[q * 4 + 2] = v.z; u[q * 4 + 3] = v.w;
      }
    } else {
#pragma unroll
      for (int q = 0; q < 16; ++q) u[q] = 0.f;
    }
#pragma unroll
    for (int j = 0; j < 16; ++j) {
      int kk = kcl + j;
      xs[kk * 128 + (rload ^ (kk & 28))] = u[j];
    }
    __syncthreads();
#pragma unroll 4
    for (int kk = 0; kk < 32; ++kk) {
      int sw = kk & 28;
      float4 xa = *(const float4*)&xs[kk * 128 + (r0 ^ sw)];
      float4 xb = *(const float4*)&xs[kk * 128 + ((64 + r0) ^ sw)];
      float4 wa = *(const float4*)&ws[kk * 128 + c0];
      float4 wb = *(const float4*)&ws[kk * 128 + 64 + c0];
      float xr[8] = {xa.x, xa.y, xa.z, xa.w, xb.x, xb.y, xb.z, xb.w};
      float wc[8] = {wa.x, wa.y, wa.z, wa.w, wb.x, wb.y, wb.z, wb.w};
#pragma unroll
      for (int i = 0; i < 8; ++i)
#pragma unroll
        for (int j = 0; j < 8; ++j) acc[i][j] += xr[i] * wc[j];
    }
  }
  // hoisted bias vectors for this thread's columns
  float4 cA0 = *(const float4*)&cb[c0];
  float4 cA1 = *(const float4*)&cb[64 + c0];
  float4 cB0 = *(const float4*)&cb[128 + c0];
  float4 cB1 = *(const float4*)&cb[128 + 64 + c0];
  float4 cC0 = *(const float4*)&cb[256 + c0];
  float4 cC1 = *(const float4*)&cb[256 + 64 + c0];
  float4 b30 = *(const float4*)&b3[c0];
  float4 b31 = *(const float4*)&b3[64 + c0];
#pragma unroll
  for (int i = 0; i < 8; ++i) {
    int rl = (i < 4) ? (r0 + i) : (64 + r0 + i - 4);
    int gr = row0 + rl;
    if (gr < n) {
      float v3 = u3[gr], v2 = u2[gr], v1 = u1[gr];
      float4 o0, o1;
      o0.x = acc[i][0] + v3 * cA0.x + v2 * cB0.x + v1 * cC0.x + b30.x;
      o0.y = acc[i][1] + v3 * cA0.y + v2 * cB0.y + v1 * cC0.y + b30.y;
      o0.z = acc[i][2] + v3 * cA0.z + v2 * cB0.z + v1 * cC0.z + b30.z;
      o0.w = acc[i][3] + v3 * cA0.w + v2 * cB0.w + v1 * cC0.w + b30.w;
      o1.x = acc[i][4] + v3 * cA1.x + v2 * cB1.x + v1 * cC1.x + b31.x;
      o1.y = acc[i][5] + v3 * cA1.y + v2 * cB1.y + v1 * cC1.y + b31.y;
      o1.z = acc[i][6] + v3 * cA1.z + v2 * cB1.z + v1 * cC1.z + b31.z;
      o1.w = acc[i][7] + v3 * cA1.w + v2 * cB1.w + v1 * cC1.w + b31.w;
      float* gp = g + (size_t)gr * DEMB;
      *(float4*)(gp + c0) = o0;
      *(float4*)(gp + 64 + c0) = o1;
    }
  }
}

extern "C" void kernel_launch(void* const* d_in, const int* in_sizes, int n_in,
                              void* d_out, int out_size, void* d_ws, size_t ws_size,
                              hipStream_t stream) {
  const float* x0 = (const float*)d_in[0];
  const int* ei = (const int*)d_in[1];
  const float* lin = (const float*)d_in[2];
  const float* gcn = (const float*)d_in[3];
  const float* gb = (const float*)d_in[4];
  float* out = (float*)d_out;

  int N = in_sizes[0] / DEMB;
  int E = in_sizes[1] / 2;
  int L = in_sizes[2] / (DEMB * DEMB);  // = 4

  char* w = (char*)d_ws;
  auto carve = [&](size_t bytes) {
    char* p = w;
    w += (bytes + 255) & ~(size_t)255;
    return p;
  };
  float* Ms   = (float*)carve((size_t)L * DEMB * DEMB * 4);
  float* A1   = (float*)carve((size_t)DEMB * DEMB * 4);
  float* A2   = (float*)carve((size_t)DEMB * DEMB * 4);
  float* wtR  = (float*)carve((size_t)DEMB * DEMB * 4);
  float* cb   = (float*)carve((size_t)3 * DEMB * 4);
  float* dinv = (float*)carve((size_t)N * 4);
  float* dnv2 = (float*)carve((size_t)N * 4);
  int* deg    = (int*)carve((size_t)N * 4);
  int* off    = (int*)carve((size_t)(N + 1) * 4);
  int* cur    = (int*)carve((size_t)N * 4);
  int* bsum   = (int*)carve(256 * 4);
  int* boff   = (int*)carve(256 * 4);
  int* csr    = (int*)carve((size_t)E * 4);
  float* u1   = (float*)carve((size_t)N * 4);
  float* u2   = (float*)carve((size_t)N * 4);
  float* u3   = (float*)carve((size_t)N * 4);
  float* a1   = (float*)carve((size_t)N * 4);
  float* g    = (float*)carve((size_t)N * DEMB * 4);
  float* a2   = (float*)cur;   // int buffers free after kfill
  float* a3   = (float*)deg;
  (void)ws_size; (void)n_in; (void)out_size;

  int nbN = (N + 255) / 256;
  int nbE = (E + 255) / 256;

  // weight/bias precompute
  kwc<<<L * DEMB, DEMB, 0, stream>>>(gcn, lin, Ms);
  ksg<<<DEMB, DEMB, 0, stream>>>(Ms + 16384, Ms, A1, 0);            // A1 = M1@M0
  ksg<<<DEMB, DEMB, 0, stream>>>(Ms + 2 * 16384, A1, A2, 0);        // A2 = M2@A1
  ksg<<<DEMB, DEMB, 0, stream>>>(Ms + 3 * 16384, A2, wtR, 1);       // wtR[k][c] = R[c][k], R=M3@A2
  kcvec<<<1, DEMB, 0, stream>>>(Ms, gb, cb);

  // graph prep
  kinit<<<nbN, 256, 0, stream>>>(deg, cur, N);
  kdeg<<<nbE, 256, 0, stream>>>(ei, deg, E);
  kdinv<<<nbN, 256, 0, stream>>>(deg, dinv, dnv2, N);
  kscan1<<<nbN, 256, 0, stream>>>(deg, off, bsum, N);
  kscan2<<<1, 256, 0, stream>>>(bsum, boff, nbN, off, N, E);
  kscan3<<<nbN, 256, 0, stream>>>(off, boff, N);
  kfill<<<nbE, 256, 0, stream>>>(ei, off, cur, csr, E);

  // u-vectors (bias propagation): u1 = S.1, u2 = S.u1, u3 = S.u2
  kspmv<<<nbN, 256, 0, stream>>>(dinv, dinv, csr, off, u1, a1, N);
  kspmv<<<nbN, 256, 0, stream>>>(a1, dinv, csr, off, u2, a2, N);
  kspmv<<<nbN, 256, 0, stream>>>(a2, dinv, csr, off, u3, a3, N);

  // 4 chained aggregations: x -> g -> out -> g -> out (raw y4)
  kagg<0><<<(N + 3) / 4, 256, 0, stream>>>(x0, csr, off, dinv, dnv2, g, N);
  kagg<1><<<(N + 3) / 4, 256, 0, stream>>>(g, csr, off, dinv, dnv2, out, N);
  kagg<1><<<(N + 3) / 4, 256, 0, stream>>>(out, csr, off, dinv, dnv2, g, N);
  kagg<2><<<(N + 3) / 4, 256, 0, stream>>>(g, csr, off, dinv, dnv2, out, N);

  // single fused GEMM with rank-1 bias terms, in-place on out
  kgemm<<<(N + 127) / 128, 256, 0, stream>>>(out, wtR, u1, u2, u3, cb, gb + 3 * DEMB, out, N);
}

// Round 3
// 268.634 us; speedup vs baseline: 1.6923x; 1.3113x over previous
//
#include <hip/hip_runtime.h>

#define DEMB 128

typedef __attribute__((ext_vector_type(8))) _Float16 half8;
typedef __attribute__((ext_vector_type(4))) _Float16 half4;
typedef __attribute__((ext_vector_type(4))) float f32x4;

// ---------- Ms[l] = gcn_l @ lin_l (row-major), grid L*128, block 128
__global__ void kwc(const float* __restrict__ gcn, const float* __restrict__ lin,
                    float* __restrict__ Ms) {
  __shared__ float sa[128];
  int l = blockIdx.x >> 7, i = blockIdx.x & 127, j = threadIdx.x;
  sa[j] = gcn[((size_t)l * 128 + i) * 128 + j];
  __syncthreads();
  float acc = 0.f;
#pragma unroll 8
  for (int k = 0; k < 128; ++k) acc += sa[k] * lin[((size_t)l * 128 + k) * 128 + j];
  Ms[((size_t)l * 128 + i) * 128 + j] = acc;
}

// ---------- small 128x128 GEMM: C = A@B (row-major, fp32 out)
__global__ void ksg(const float* __restrict__ A, const float* __restrict__ B,
                    float* __restrict__ C) {
  __shared__ float sa[128];
  int i = blockIdx.x, j = threadIdx.x;
  sa[j] = A[i * 128 + j];
  __syncthreads();
  float acc = 0.f;
#pragma unroll 8
  for (int k = 0; k < 128; ++k) acc += sa[k] * B[k * 128 + j];
  C[i * 128 + j] = acc;
}

// ---------- same, fp16 out (row-major): Rh[c][k]
__global__ void ksgh(const float* __restrict__ A, const float* __restrict__ B,
                     _Float16* __restrict__ C) {
  __shared__ float sa[128];
  int i = blockIdx.x, j = threadIdx.x;
  sa[j] = A[i * 128 + j];
  __syncthreads();
  float acc = 0.f;
#pragma unroll 8
  for (int k = 0; k < 128; ++k) acc += sa[k] * B[k * 128 + j];
  C[i * 128 + j] = (_Float16)acc;
}

// ---------- bias chain vectors: cb[0]=M3M2M1b0, cb[1]=M3M2b1, cb[2]=M3b2
__global__ void kcvec(const float* __restrict__ Ms, const float* __restrict__ gb,
                      float* __restrict__ cb) {
  __shared__ float t0[128], t1[128];
  int j = threadIdx.x;
  const float* M1 = Ms + 16384;
  const float* M2 = Ms + 2 * 16384;
  const float* M3 = Ms + 3 * 16384;
  float a;
  t0[j] = gb[j]; __syncthreads();
  a = 0.f; for (int k = 0; k < 128; ++k) a += M1[j * 128 + k] * t0[k];
  t1[j] = a; __syncthreads();
  a = 0.f; for (int k = 0; k < 128; ++k) a += M2[j * 128 + k] * t1[k];
  __syncthreads(); t0[j] = a; __syncthreads();
  a = 0.f; for (int k = 0; k < 128; ++k) a += M3[j * 128 + k] * t0[k];
  cb[j] = a;
  __syncthreads(); t0[j] = gb[128 + j]; __syncthreads();
  a = 0.f; for (int k = 0; k < 128; ++k) a += M2[j * 128 + k] * t0[k];
  t1[j] = a; __syncthreads();
  a = 0.f; for (int k = 0; k < 128; ++k) a += M3[j * 128 + k] * t1[k];
  cb[128 + j] = a;
  __syncthreads(); t0[j] = gb[256 + j]; __syncthreads();
  a = 0.f; for (int k = 0; k < 128; ++k) a += M3[j * 128 + k] * t0[k];
  cb[256 + j] = a;
}

// ---------- graph prep
__global__ void kinit(int* __restrict__ deg, int* __restrict__ cur, int n) {
  int i = blockIdx.x * 256 + threadIdx.x;
  if (i < n) { deg[i] = 1; cur[i] = 0; }
}

__global__ void kdeg(const int* __restrict__ ei, int* __restrict__ deg, int etot) {
  int i = blockIdx.x * 256 + threadIdx.x;
  if (i < etot) atomicAdd(&deg[ei[etot + i]], 1);
}

// scan step 1, with dinv/dinv2 computation fused
__global__ void kscan1(const int* __restrict__ deg, int* __restrict__ off,
                       int* __restrict__ bsum, float* __restrict__ dinv,
                       float* __restrict__ dinv2, int n) {
  __shared__ int s[256];
  int t = threadIdx.x, i = blockIdx.x * 256 + t;
  int c = 0;
  if (i < n) {
    int d = deg[i];
    c = d - 1;
    float dv = rsqrtf((float)d);
    dinv[i] = dv;
    dinv2[i] = dv * dv;
  }
  s[t] = c;
  __syncthreads();
  for (int o = 1; o < 256; o <<= 1) {
    int v = (t >= o) ? s[t - o] : 0;
    __syncthreads();
    s[t] += v;
    __syncthreads();
  }
  if (i < n) off[i] = s[t] - c;
  if (t == 255) bsum[blockIdx.x] = s[t];
}

__global__ void kscan2(const int* __restrict__ bsum, int* __restrict__ boff,
                       int nb, int* __restrict__ off, int n, int etot) {
  __shared__ int s[256];
  int t = threadIdx.x;
  int c = (t < nb) ? bsum[t] : 0;
  s[t] = c;
  __syncthreads();
  for (int o = 1; o < 256; o <<= 1) {
    int v = (t >= o) ? s[t - o] : 0;
    __syncthreads();
    s[t] += v;
    __syncthreads();
  }
  if (t < nb) boff[t] = s[t] - c;
  if (t == 0) off[n] = etot;
}

__global__ void kscan3(int* __restrict__ off, const int* __restrict__ boff, int n) {
  int i = blockIdx.x * 256 + threadIdx.x;
  if (i < n) off[i] += boff[i >> 8];
}

__global__ void kfill(const int* __restrict__ ei, const int* __restrict__ off,
                      int* __restrict__ cur, int* __restrict__ csr, int etot) {
  int i = blockIdx.x * 256 + threadIdx.x;
  if (i < etot) {
    int d = ei[etot + i];
    int p = atomicAdd(&cur[d], 1);
    csr[off[d] + p] = ei[i];
  }
}

// ---------- scalar SpMV for bias u-vectors
__global__ void kspmv(const float* __restrict__ a_in, const float* __restrict__ dinv,
                      const int* __restrict__ csr, const int* __restrict__ off,
                      float* __restrict__ u_out, float* __restrict__ a_out, int n) {
  int i = blockIdx.x * 256 + threadIdx.x;
  if (i >= n) return;
  float s = a_in[i];
  int e = off[i], end = off[i + 1];
  for (; e < end; ++e) s += a_in[csr[e]];
  float u = dinv[i] * s;
  u_out[i] = u;
  a_out[i] = dinv[i] * u;
}

// ---------- prescale: xh[i][c] = fp16(x[i][c] * dinv[i])
__global__ void kpre(const float* __restrict__ x, const float* __restrict__ dinv,
                     _Float16* __restrict__ xh, int n) {
  int gid = blockIdx.x * 256 + threadIdx.x;
  if (gid >= n * 32) return;
  int r = gid >> 5, c = (gid & 31) * 4;
  float d = dinv[r];
  float4 v = *(const float4*)(x + (size_t)r * DEMB + c);
  half4 o = {(_Float16)(v.x * d), (_Float16)(v.y * d), (_Float16)(v.z * d), (_Float16)(v.w * d)};
  *(half4*)(xh + (size_t)r * DEMB + c) = o;
}

// ---------- fp16 aggregation: one wave/node, quarter-wave/edge, 16 rows in flight
// vout[i] = fp16( scale[i] * (vin[i] + sum_{src} vin[src]) )
__launch_bounds__(256)
__global__ void kagg16(const _Float16* __restrict__ vin, const int* __restrict__ csr,
                       const int* __restrict__ off, const float* __restrict__ scale,
                       _Float16* __restrict__ vout, int n) {
  int wid = (int)((blockIdx.x * 256u + threadIdx.x) >> 6);
  if (wid >= n) return;
  int lane = threadIdx.x & 63;
  int q = lane >> 4, l16 = lane & 15;
  const _Float16* base = vin + (size_t)8 * l16;
  float acc[8];
  if (q == 0) {
    half8 sv = *(const half8*)(base + (size_t)wid * DEMB);
#pragma unroll
    for (int j = 0; j < 8; ++j) acc[j] = (float)sv[j];
  } else {
#pragma unroll
    for (int j = 0; j < 8; ++j) acc[j] = 0.f;
  }
  int end = off[wid + 1];
  for (int e = off[wid] + 4 * q; e < end; e += 16) {
    int em = end - 1;
    int i0 = csr[e];
    int i1 = csr[min(e + 1, em)];
    int i2 = csr[min(e + 2, em)];
    int i3 = csr[min(e + 3, em)];
    float w1 = (e + 1 < end) ? 1.f : 0.f;
    float w2 = (e + 2 < end) ? 1.f : 0.f;
    float w3 = (e + 3 < end) ? 1.f : 0.f;
    half8 r0 = *(const half8*)(base + (size_t)i0 * DEMB);
    half8 r1 = *(const half8*)(base + (size_t)i1 * DEMB);
    half8 r2 = *(const half8*)(base + (size_t)i2 * DEMB);
    half8 r3 = *(const half8*)(base + (size_t)i3 * DEMB);
#pragma unroll
    for (int j = 0; j < 8; ++j)
      acc[j] += (float)r0[j] + w1 * (float)r1[j] + w2 * (float)r2[j] + w3 * (float)r3[j];
  }
#pragma unroll
  for (int j = 0; j < 8; ++j) {
    acc[j] += __shfl_xor(acc[j], 16);
    acc[j] += __shfl_xor(acc[j], 32);
  }
  if (q == 0) {
    float s = scale[wid];
    half8 o;
#pragma unroll
    for (int j = 0; j < 8; ++j) o[j] = (_Float16)(acc[j] * s);
    *(half8*)(vout + (size_t)wid * DEMB + 8 * l16) = o;
  }
}

// ---------- final MFMA GEMM: out[r][c] = sum_k y[r][k]*Rh[c][k]
//            + u3[r]*cb[c] + u2[r]*cb[128+c] + u1[r]*cb[256+c] + b3[c]
__launch_bounds__(256)
__global__ void kgemm16(const _Float16* __restrict__ y, const _Float16* __restrict__ Rh,
                        const float* __restrict__ u1, const float* __restrict__ u2,
                        const float* __restrict__ u3, const float* __restrict__ cb,
                        const float* __restrict__ b3, float* __restrict__ out, int n) {
  int t = threadIdx.x;
  int wv = t >> 6, lane = t & 63;
  int l16 = lane & 15, g = lane >> 4;
  int row0 = blockIdx.x * 128 + wv * 32;  // this wave: rows row0..row0+31, all 128 cols
  f32x4 acc[2][8];
#pragma unroll
  for (int w = 0; w < 2; ++w)
#pragma unroll
    for (int n8 = 0; n8 < 8; ++n8) acc[w][n8] = (f32x4){0.f, 0.f, 0.f, 0.f};

#pragma unroll
  for (int k0 = 0; k0 < 128; k0 += 32) {
    half8 a0 = *(const half8*)(y + (size_t)(row0 + l16) * DEMB + k0 + g * 8);
    half8 a1 = *(const half8*)(y + (size_t)(row0 + 16 + l16) * DEMB + k0 + g * 8);
#pragma unroll
    for (int n8 = 0; n8 < 8; ++n8) {
      half8 b = *(const half8*)(Rh + (size_t)(n8 * 16 + l16) * DEMB + k0 + g * 8);
      acc[0][n8] = __builtin_amdgcn_mfma_f32_16x16x32_f16(a0, b, acc[0][n8], 0, 0, 0);
      acc[1][n8] = __builtin_amdgcn_mfma_f32_16x16x32_f16(a1, b, acc[1][n8], 0, 0, 0);
    }
  }
#pragma unroll
  for (int n8 = 0; n8 < 8; ++n8) {
    int col = n8 * 16 + l16;
    float cA = cb[col], cB = cb[128 + col], cC = cb[256 + col], bb = b3[col];
#pragma unroll
    for (int w = 0; w < 2; ++w)
#pragma unroll
      for (int r = 0; r < 4; ++r) {
        int row = row0 + w * 16 + g * 4 + r;
        if (row < n) {
          out[(size_t)row * DEMB + col] =
              acc[w][n8][r] + u3[row] * cA + u2[row] * cB + u1[row] * cC + bb;
        }
      }
  }
}

extern "C" void kernel_launch(void* const* d_in, const int* in_sizes, int n_in,
                              void* d_out, int out_size, void* d_ws, size_t ws_size,
                              hipStream_t stream) {
  const float* x0 = (const float*)d_in[0];
  const int* ei = (const int*)d_in[1];
  const float* lin = (const float*)d_in[2];
  const float* gcn = (const float*)d_in[3];
  const float* gb = (const float*)d_in[4];
  float* out = (float*)d_out;

  int N = in_sizes[0] / DEMB;
  int E = in_sizes[1] / 2;
  int L = in_sizes[2] / (DEMB * DEMB);  // = 4
  int NP = (N + 127) & ~127;            // padded rows for MFMA tiles

  char* w = (char*)d_ws;
  auto carve = [&](size_t bytes) {
    char* p = w;
    w += (bytes + 255) & ~(size_t)255;
    return p;
  };
  float* Ms    = (float*)carve((size_t)L * DEMB * DEMB * 4);
  float* A1    = (float*)carve((size_t)DEMB * DEMB * 4);
  float* A2    = (float*)carve((size_t)DEMB * DEMB * 4);
  _Float16* Rh = (_Float16*)carve((size_t)DEMB * DEMB * 2);
  float* cb    = (float*)carve((size_t)3 * DEMB * 4);
  float* dinv  = (float*)carve((size_t)N * 4);
  float* dnv2  = (float*)carve((size_t)N * 4);
  int* deg     = (int*)carve((size_t)N * 4);
  int* off     = (int*)carve((size_t)(N + 1) * 4);
  int* cur     = (int*)carve((size_t)N * 4);
  int* bsum    = (int*)carve(256 * 4);
  int* boff    = (int*)carve(256 * 4);
  int* csr     = (int*)carve((size_t)E * 4);
  float* u1    = (float*)carve((size_t)N * 4);
  float* u2    = (float*)carve((size_t)N * 4);
  float* u3    = (float*)carve((size_t)N * 4);
  float* a1    = (float*)carve((size_t)N * 4);
  _Float16* ha = (_Float16*)carve((size_t)NP * DEMB * 2);
  _Float16* hb = (_Float16*)carve((size_t)NP * DEMB * 2);
  float* a2    = (float*)cur;  // int buffers free after kfill
  float* a3    = (float*)deg;  // deg free after kscan1
  (void)ws_size; (void)n_in; (void)out_size;

  int nbN = (N + 255) / 256;
  int nbE = (E + 255) / 256;

  // weight/bias precompute
  kwc<<<L * DEMB, DEMB, 0, stream>>>(gcn, lin, Ms);
  ksg<<<DEMB, DEMB, 0, stream>>>(Ms + 16384, Ms, A1);           // A1 = M1@M0
  ksg<<<DEMB, DEMB, 0, stream>>>(Ms + 2 * 16384, A1, A2);       // A2 = M2@A1
  ksgh<<<DEMB, DEMB, 0, stream>>>(Ms + 3 * 16384, A2, Rh);      // Rh = fp16(M3@A2), row-major [c][k]
  kcvec<<<1, DEMB, 0, stream>>>(Ms, gb, cb);

  // graph prep
  kinit<<<nbN, 256, 0, stream>>>(deg, cur, N);
  kdeg<<<nbE, 256, 0, stream>>>(ei, deg, E);
  kscan1<<<nbN, 256, 0, stream>>>(deg, off, bsum, dinv, dnv2, N);
  kscan2<<<1, 256, 0, stream>>>(bsum, boff, nbN, off, N, E);
  kscan3<<<nbN, 256, 0, stream>>>(off, boff, N);
  kfill<<<nbE, 256, 0, stream>>>(ei, off, cur, csr, E);

  // u-vectors (bias propagation): u1 = S.1, u2 = S.u1, u3 = S.u2
  kspmv<<<nbN, 256, 0, stream>>>(dinv, dinv, csr, off, u1, a1, N);
  kspmv<<<nbN, 256, 0, stream>>>(a1, dinv, csr, off, u2, a2, N);
  kspmv<<<nbN, 256, 0, stream>>>(a2, dinv, csr, off, u3, a3, N);

  // prescale + 4 chained fp16 aggregations: ha -> hb -> ha -> hb -> ha
  kpre<<<(N * 32 + 255) / 256, 256, 0, stream>>>(x0, dinv, ha, N);
  kagg16<<<(N + 3) / 4, 256, 0, stream>>>(ha, csr, off, dnv2, hb, N);
  kagg16<<<(N + 3) / 4, 256, 0, stream>>>(hb, csr, off, dnv2, ha, N);
  kagg16<<<(N + 3) / 4, 256, 0, stream>>>(ha, csr, off, dnv2, hb, N);
  kagg16<<<(N + 3) / 4, 256, 0, stream>>>(hb, csr, off, dinv, ha, N);  // raw y4 (fp16)

  // final fp16-MFMA GEMM with rank-1 bias terms -> fp32 out
  kgemm16<<<(N + 127) / 128, 256, 0, stream>>>(ha, Rh, u1, u2, u3, cb, gb + 3 * DEMB, out, N);
}

// Round 4
// 221.826 us; speedup vs baseline: 2.0494x; 1.2110x over previous
//
#include <hip/hip_runtime.h>

#define DEMB 128

typedef __attribute__((ext_vector_type(8))) _Float16 half8;
typedef __attribute__((ext_vector_type(4))) _Float16 half4;
typedef __attribute__((ext_vector_type(4))) float f32x4;

// ---------- Ms[l] = gcn_l @ lin_l (row-major), grid L*128, block 128
__global__ void kwc(const float* __restrict__ gcn, const float* __restrict__ lin,
                    float* __restrict__ Ms) {
  __shared__ float sa[128];
  int l = blockIdx.x >> 7, i = blockIdx.x & 127, j = threadIdx.x;
  sa[j] = gcn[((size_t)l * 128 + i) * 128 + j];
  __syncthreads();
  float acc = 0.f;
#pragma unroll 8
  for (int k = 0; k < 128; ++k) acc += sa[k] * lin[((size_t)l * 128 + k) * 128 + j];
  Ms[((size_t)l * 128 + i) * 128 + j] = acc;
}

// ---------- stage 2: A1 = M1@M0, B1 = M3@M2, v0 = M1@b0, cC = M3@b2
__global__ void kst2(const float* __restrict__ Ms, const float* __restrict__ gb,
                     float* __restrict__ A1, float* __restrict__ B1,
                     float* __restrict__ v0, float* __restrict__ cb) {
  const float* M0 = Ms;
  const float* M1 = Ms + 16384;
  const float* M2 = Ms + 2 * 16384;
  const float* M3 = Ms + 3 * 16384;
  __shared__ float sa[128];
  int b = blockIdx.x, j = threadIdx.x;
  if (b < 128) {
    sa[j] = M1[b * 128 + j];
    __syncthreads();
    float acc = 0.f;
#pragma unroll 8
    for (int k = 0; k < 128; ++k) acc += sa[k] * M0[k * 128 + j];
    A1[b * 128 + j] = acc;
  } else if (b < 256) {
    int i = b - 128;
    sa[j] = M3[i * 128 + j];
    __syncthreads();
    float acc = 0.f;
#pragma unroll 8
    for (int k = 0; k < 128; ++k) acc += sa[k] * M2[k * 128 + j];
    B1[i * 128 + j] = acc;
  } else if (b == 256) {
    sa[j] = gb[j];
    __syncthreads();
    float acc = 0.f;
#pragma unroll 8
    for (int k = 0; k < 128; ++k) acc += M1[j * 128 + k] * sa[k];
    v0[j] = acc;
  } else {
    sa[j] = gb[2 * 128 + j];
    __syncthreads();
    float acc = 0.f;
#pragma unroll 8
    for (int k = 0; k < 128; ++k) acc += M3[j * 128 + k] * sa[k];
    cb[256 + j] = acc;  // cC
  }
}

// ---------- stage 3: Rh = fp16(B1@A1) row-major [c][k], cA = B1@v0, cB = B1@b1
__global__ void kst3(const float* __restrict__ A1, const float* __restrict__ B1,
                     const float* __restrict__ v0, const float* __restrict__ gb,
                     _Float16* __restrict__ Rh, float* __restrict__ cb) {
  __shared__ float sa[128];
  int b = blockIdx.x, j = threadIdx.x;
  if (b < 128) {
    sa[j] = B1[b * 128 + j];
    __syncthreads();
    float acc = 0.f;
#pragma unroll 8
    for (int k = 0; k < 128; ++k) acc += sa[k] * A1[k * 128 + j];
    Rh[b * 128 + j] = (_Float16)acc;
  } else if (b == 128) {
    sa[j] = v0[j];
    __syncthreads();
    float acc = 0.f;
#pragma unroll 8
    for (int k = 0; k < 128; ++k) acc += B1[j * 128 + k] * sa[k];
    cb[j] = acc;  // cA
  } else {
    sa[j] = gb[128 + j];
    __syncthreads();
    float acc = 0.f;
#pragma unroll 8
    for (int k = 0; k < 128; ++k) acc += B1[j * 128 + k] * sa[k];
    cb[128 + j] = acc;  // cB
  }
}

// ---------- graph prep
__global__ void kinit(int* __restrict__ deg, int n) {
  int i = blockIdx.x * 256 + threadIdx.x;
  if (i < n) deg[i] = 0;  // edge-only count; self loop folded in kscan1
}

__global__ void kdeg(const int* __restrict__ ei, int* __restrict__ deg, int etot) {
  int i = blockIdx.x * 256 + threadIdx.x;
  if (i < etot) atomicAdd(&deg[ei[etot + i]], 1);
}

// scan step 1 (+ dinv/dinv2, self-loop +1 folded)
__global__ void kscan1(const int* __restrict__ deg, int* __restrict__ off,
                       int* __restrict__ bsum, float* __restrict__ dinv,
                       float* __restrict__ dinv2, int n) {
  __shared__ int s[256];
  int t = threadIdx.x, i = blockIdx.x * 256 + t;
  int c = 0;
  if (i < n) {
    c = deg[i];
    float dv = rsqrtf((float)(c + 1));
    dinv[i] = dv;
    dinv2[i] = dv * dv;
  }
  s[t] = c;
  __syncthreads();
  for (int o = 1; o < 256; o <<= 1) {
    int v = (t >= o) ? s[t - o] : 0;
    __syncthreads();
    s[t] += v;
    __syncthreads();
  }
  if (i < n) off[i] = s[t] - c;
  if (t == 255) bsum[blockIdx.x] = s[t];
}

__global__ void kscan2(const int* __restrict__ bsum, int* __restrict__ boff,
                       int nb, int* __restrict__ off, int n, int etot) {
  __shared__ int s[256];
  int t = threadIdx.x;
  int c = (t < nb) ? bsum[t] : 0;
  s[t] = c;
  __syncthreads();
  for (int o = 1; o < 256; o <<= 1) {
    int v = (t >= o) ? s[t - o] : 0;
    __syncthreads();
    s[t] += v;
    __syncthreads();
  }
  if (t < nb) boff[t] = s[t] - c;
  if (t == 0) off[n] = etot;
}

__global__ void kscan3(int* __restrict__ off, const int* __restrict__ boff,
                       int* __restrict__ cur, int n) {
  int i = blockIdx.x * 256 + threadIdx.x;
  if (i < n) {
    int o = off[i] + boff[i >> 8];
    off[i] = o;
    cur[i] = o;
  }
}

__global__ void kfill(const int* __restrict__ ei, int* __restrict__ cur,
                      int* __restrict__ csr, int etot) {
  int i = blockIdx.x * 256 + threadIdx.x;
  if (i < etot) {
    int d = ei[etot + i];
    int p = atomicAdd(&cur[d], 1);
    csr[p] = ei[i];
  }
}

// ---------- prescale: xh[i][c] = fp16(x[i][c] * dinv[i])
__global__ void kpre(const float* __restrict__ x, const float* __restrict__ dinv,
                     _Float16* __restrict__ xh, int n) {
  int gid = blockIdx.x * 256 + threadIdx.x;
  if (gid >= n * 32) return;
  int r = gid >> 5, c = (gid & 31) * 4;
  float d = dinv[r];
  float4 v = *(const float4*)(x + (size_t)r * DEMB + c);
  half4 o = {(_Float16)(v.x * d), (_Float16)(v.y * d), (_Float16)(v.z * d), (_Float16)(v.w * d)};
  *(half4*)(xh + (size_t)r * DEMB + c) = o;
}

// ---------- fp16 aggregation: quarter-wave (16 lanes) per node, no cross-lane reduce.
// vout[i] = fp16( scale[i] * (vin[i] + sum_src vin[src]) )
// WITHU: also u = dinv[i]*(a_in[i] + sum_src a_in[src]); u_out[i]=u; a_out[i]=dinv[i]*u
template <int WITHU>
__launch_bounds__(256)
__global__ void kagg16(const _Float16* __restrict__ vin, const int* __restrict__ csr,
                       const int* __restrict__ off, const float* __restrict__ scale,
                       const float* __restrict__ dinv, const float* __restrict__ a_in,
                       float* __restrict__ u_out, float* __restrict__ a_out,
                       _Float16* __restrict__ vout, int n) {
  int node = (int)((blockIdx.x * 256u + threadIdx.x) >> 4);
  if (node >= n) return;
  int l16 = threadIdx.x & 15;
  const _Float16* base = vin + 8 * l16;
  half8 sv = *(const half8*)(base + (size_t)node * DEMB);
  float acc[8];
#pragma unroll
  for (int j = 0; j < 8; ++j) acc[j] = (float)sv[j];
  float s = WITHU ? a_in[node] : 0.f;
  int e = off[node], end = off[node + 1];
  // 8-deep
  for (; e + 8 <= end; e += 8) {
    int i0 = csr[e], i1 = csr[e + 1], i2 = csr[e + 2], i3 = csr[e + 3];
    int i4 = csr[e + 4], i5 = csr[e + 5], i6 = csr[e + 6], i7 = csr[e + 7];
    half8 r0 = *(const half8*)(base + (size_t)i0 * DEMB);
    half8 r1 = *(const half8*)(base + (size_t)i1 * DEMB);
    half8 r2 = *(const half8*)(base + (size_t)i2 * DEMB);
    half8 r3 = *(const half8*)(base + (size_t)i3 * DEMB);
    half8 r4 = *(const half8*)(base + (size_t)i4 * DEMB);
    half8 r5 = *(const half8*)(base + (size_t)i5 * DEMB);
    half8 r6 = *(const half8*)(base + (size_t)i6 * DEMB);
    half8 r7 = *(const half8*)(base + (size_t)i7 * DEMB);
    if (WITHU)
      s += a_in[i0] + a_in[i1] + a_in[i2] + a_in[i3] +
           a_in[i4] + a_in[i5] + a_in[i6] + a_in[i7];
#pragma unroll
    for (int j = 0; j < 8; ++j)
      acc[j] += ((float)r0[j] + (float)r1[j]) + ((float)r2[j] + (float)r3[j]) +
                ((float)r4[j] + (float)r5[j]) + ((float)r6[j] + (float)r7[j]);
  }
  // 4-deep
  for (; e + 4 <= end; e += 4) {
    int i0 = csr[e], i1 = csr[e + 1], i2 = csr[e + 2], i3 = csr[e + 3];
    half8 r0 = *(const half8*)(base + (size_t)i0 * DEMB);
    half8 r1 = *(const half8*)(base + (size_t)i1 * DEMB);
    half8 r2 = *(const half8*)(base + (size_t)i2 * DEMB);
    half8 r3 = *(const half8*)(base + (size_t)i3 * DEMB);
    if (WITHU) s += a_in[i0] + a_in[i1] + a_in[i2] + a_in[i3];
#pragma unroll
    for (int j = 0; j < 8; ++j)
      acc[j] += ((float)r0[j] + (float)r1[j]) + ((float)r2[j] + (float)r3[j]);
  }
  // tail (<=3)
  if (e < end) {
    int em = end - 1;
    int i0 = csr[e];
    int i1 = csr[min(e + 1, em)];
    int i2 = csr[min(e + 2, em)];
    float w1 = (e + 1 < end) ? 1.f : 0.f;
    float w2 = (e + 2 < end) ? 1.f : 0.f;
    half8 r0 = *(const half8*)(base + (size_t)i0 * DEMB);
    half8 r1 = *(const half8*)(base + (size_t)i1 * DEMB);
    half8 r2 = *(const half8*)(base + (size_t)i2 * DEMB);
    if (WITHU) s += a_in[i0] + w1 * a_in[i1] + w2 * a_in[i2];
#pragma unroll
    for (int j = 0; j < 8; ++j)
      acc[j] += (float)r0[j] + w1 * (float)r1[j] + w2 * (float)r2[j];
  }
  float sc = scale[node];
  half8 o;
#pragma unroll
  for (int j = 0; j < 8; ++j) o[j] = (_Float16)(acc[j] * sc);
  *(half8*)(vout + (size_t)node * DEMB + 8 * l16) = o;
  if (WITHU && l16 == 0) {
    float dv = dinv[node];
    float u = dv * s;
    u_out[node] = u;
    a_out[node] = dv * u;
  }
}

// ---------- final MFMA GEMM: out[r][c] = sum_k y[r][k]*Rh[c][k]
//            + u3[r]*cb[c] + u2[r]*cb[128+c] + u1[r]*cb[256+c] + b3[c]
__launch_bounds__(256)
__global__ void kgemm16(const _Float16* __restrict__ y, const _Float16* __restrict__ Rh,
                        const float* __restrict__ u1, const float* __restrict__ u2,
                        const float* __restrict__ u3, const float* __restrict__ cb,
                        const float* __restrict__ b3, float* __restrict__ out, int n) {
  int t = threadIdx.x;
  int wv = t >> 6, lane = t & 63;
  int l16 = lane & 15, g = lane >> 4;
  int row0 = blockIdx.x * 128 + wv * 32;
  f32x4 acc[2][8];
#pragma unroll
  for (int w = 0; w < 2; ++w)
#pragma unroll
    for (int n8 = 0; n8 < 8; ++n8) acc[w][n8] = (f32x4){0.f, 0.f, 0.f, 0.f};

#pragma unroll
  for (int k0 = 0; k0 < 128; k0 += 32) {
    half8 a0 = *(const half8*)(y + (size_t)(row0 + l16) * DEMB + k0 + g * 8);
    half8 a1 = *(const half8*)(y + (size_t)(row0 + 16 + l16) * DEMB + k0 + g * 8);
#pragma unroll
    for (int n8 = 0; n8 < 8; ++n8) {
      half8 b = *(const half8*)(Rh + (size_t)(n8 * 16 + l16) * DEMB + k0 + g * 8);
      acc[0][n8] = __builtin_amdgcn_mfma_f32_16x16x32_f16(a0, b, acc[0][n8], 0, 0, 0);
      acc[1][n8] = __builtin_amdgcn_mfma_f32_16x16x32_f16(a1, b, acc[1][n8], 0, 0, 0);
    }
  }
#pragma unroll
  for (int n8 = 0; n8 < 8; ++n8) {
    int col = n8 * 16 + l16;
    float cA = cb[col], cB = cb[128 + col], cC = cb[256 + col], bb = b3[col];
#pragma unroll
    for (int w = 0; w < 2; ++w)
#pragma unroll
      for (int r = 0; r < 4; ++r) {
        int row = row0 + w * 16 + g * 4 + r;
        if (row < n) {
          out[(size_t)row * DEMB + col] =
              acc[w][n8][r] + u3[row] * cA + u2[row] * cB + u1[row] * cC + bb;
        }
      }
  }
}

extern "C" void kernel_launch(void* const* d_in, const int* in_sizes, int n_in,
                              void* d_out, int out_size, void* d_ws, size_t ws_size,
                              hipStream_t stream) {
  const float* x0 = (const float*)d_in[0];
  const int* ei = (const int*)d_in[1];
  const float* lin = (const float*)d_in[2];
  const float* gcn = (const float*)d_in[3];
  const float* gb = (const float*)d_in[4];
  float* out = (float*)d_out;

  int N = in_sizes[0] / DEMB;
  int E = in_sizes[1] / 2;
  int L = in_sizes[2] / (DEMB * DEMB);  // = 4
  int NP = (N + 127) & ~127;

  char* w = (char*)d_ws;
  auto carve = [&](size_t bytes) {
    char* p = w;
    w += (bytes + 255) & ~(size_t)255;
    return p;
  };
  float* Ms    = (float*)carve((size_t)L * DEMB * DEMB * 4);
  float* A1    = (float*)carve((size_t)DEMB * DEMB * 4);
  float* B1    = (float*)carve((size_t)DEMB * DEMB * 4);
  _Float16* Rh = (_Float16*)carve((size_t)DEMB * DEMB * 2);
  float* v0    = (float*)carve((size_t)DEMB * 4);
  float* cb    = (float*)carve((size_t)3 * DEMB * 4);
  float* dinv  = (float*)carve((size_t)N * 4);
  float* dnv2  = (float*)carve((size_t)N * 4);
  int* deg     = (int*)carve((size_t)N * 4);
  int* off     = (int*)carve((size_t)(N + 1) * 4);
  int* cur     = (int*)carve((size_t)N * 4);
  int* bsum    = (int*)carve(256 * 4);
  int* boff    = (int*)carve(256 * 4);
  int* csr     = (int*)carve((size_t)E * 4);
  float* u1    = (float*)carve((size_t)N * 4);
  float* u2    = (float*)carve((size_t)N * 4);
  float* u3    = (float*)carve((size_t)N * 4);
  float* a1    = (float*)carve((size_t)N * 4);
  float* a2    = (float*)carve((size_t)N * 4);
  float* a3    = (float*)carve((size_t)N * 4);
  _Float16* ha = (_Float16*)carve((size_t)NP * DEMB * 2);
  _Float16* hb = (_Float16*)carve((size_t)NP * DEMB * 2);
  (void)ws_size; (void)n_in; (void)out_size;

  int nbN = (N + 255) / 256;
  int nbE = (E + 255) / 256;
  int nbA = (N * 16 + 255) / 256;  // agg: 16 threads per node

  // weight/bias precompute (3 launches)
  kwc<<<L * DEMB, DEMB, 0, stream>>>(gcn, lin, Ms);
  kst2<<<258, DEMB, 0, stream>>>(Ms, gb, A1, B1, v0, cb);
  kst3<<<130, DEMB, 0, stream>>>(A1, B1, v0, gb, Rh, cb);

  // graph prep (6 launches)
  kinit<<<nbN, 256, 0, stream>>>(deg, N);
  kdeg<<<nbE, 256, 0, stream>>>(ei, deg, E);
  kscan1<<<nbN, 256, 0, stream>>>(deg, off, bsum, dinv, dnv2, N);
  kscan2<<<1, 256, 0, stream>>>(bsum, boff, nbN, off, N, E);
  kscan3<<<nbN, 256, 0, stream>>>(off, boff, cur, N);
  kfill<<<nbE, 256, 0, stream>>>(ei, cur, csr, E);

  // prescale + 4 chained fp16 aggregations with fused u-chain
  kpre<<<(N * 32 + 255) / 256, 256, 0, stream>>>(x0, dinv, ha, N);
  kagg16<1><<<nbA, 256, 0, stream>>>(ha, csr, off, dnv2, dinv, dinv, u1, a1, hb, N);
  kagg16<1><<<nbA, 256, 0, stream>>>(hb, csr, off, dnv2, dinv, a1, u2, a2, ha, N);
  kagg16<1><<<nbA, 256, 0, stream>>>(ha, csr, off, dnv2, dinv, a2, u3, a3, hb, N);
  kagg16<0><<<nbA, 256, 0, stream>>>(hb, csr, off, dinv, dinv, nullptr, nullptr, nullptr, ha, N);

  // final fp16-MFMA GEMM with rank-1 bias terms -> fp32 out
  kgemm16<<<(N + 127) / 128, 256, 0, stream>>>(ha, Rh, u1, u2, u3, cb, gb + 3 * DEMB, out, N);
}